// Round 9
// baseline (258.449 us; speedup 1.0000x reference)
//
#include <hip/hip_runtime.h>
#include <hip/hip_bf16.h>
#include <math.h>
#include <stdint.h>

#define BDIM 8192
#define DDIM 512
#define NT   64        // BDIM / 128
#define BK   64        // K-step staged in LDS
#define TEMP 10.0f

typedef __attribute__((ext_vector_type(8))) short bf16x8;
typedef __attribute__((ext_vector_type(4))) float f32x4;
typedef unsigned long long u64;
typedef unsigned int u32;

__device__ __forceinline__ unsigned short f2bf(float f) {
  unsigned int x = __float_as_uint(f);
  x += 0x7fffu + ((x >> 16) & 1u);   // round-to-nearest-even
  return (unsigned short)(x >> 16);
}

// async global->LDS, 16B per lane; LDS dest = wave-uniform base + lane*16
__device__ __forceinline__ void gld16(const void* gptr, void* lptr) {
  __builtin_amdgcn_global_load_lds((const __attribute__((address_space(1))) u32*)gptr,
                                   (__attribute__((address_space(3))) u32*)lptr, 16, 0, 0);
}

// Butterfly sum over 16-lane groups via DPP (xor 1,2,7,15 spans 4-bit space).
__device__ __forceinline__ float red16_dpp(float x) {
  x += __int_as_float(__builtin_amdgcn_mov_dpp(__float_as_int(x), 0xB1, 0xF, 0xF, true));
  x += __int_as_float(__builtin_amdgcn_mov_dpp(__float_as_int(x), 0x4E, 0xF, 0xF, true));
  x += __int_as_float(__builtin_amdgcn_mov_dpp(__float_as_int(x), 0x141, 0xF, 0xF, true));
  x += __int_as_float(__builtin_amdgcn_mov_dpp(__float_as_int(x), 0x140, 0xF, 0xF, true));
  return x;
}

// ---------------- kernel 1: normalize rows, fold TEMP3 into u, store bf16 ----
__global__ __launch_bounds__(256) void knorm(const float* __restrict__ cnn,
                                             const float* __restrict__ rnn,
                                             unsigned short* __restrict__ u,
                                             unsigned short* __restrict__ v) {
  int wid = threadIdx.x >> 6, lane = threadIdx.x & 63;
  int gw = blockIdx.x * 4 + wid;          // 0 .. 2*BDIM-1
  const float* src;
  unsigned short* dst;
  int row;
  float mul;
  if (gw < BDIM) { src = cnn; dst = u; row = gw; mul = TEMP; }
  else           { src = rnn; dst = v; row = gw - BDIM; mul = 1.0f; }
  const float* p = src + (size_t)row * DDIM + lane * 8;
  float4 a0 = *(const float4*)p;
  float4 a1 = *(const float4*)(p + 4);
  float ss = a0.x*a0.x + a0.y*a0.y + a0.z*a0.z + a0.w*a0.w
           + a1.x*a1.x + a1.y*a1.y + a1.z*a1.z + a1.w*a1.w;
#pragma unroll
  for (int m = 1; m <= 32; m <<= 1) ss += __shfl_xor(ss, m);
  float inv = mul / sqrtf(ss);
  unsigned short o[8];
  o[0] = f2bf(a0.x * inv); o[1] = f2bf(a0.y * inv);
  o[2] = f2bf(a0.z * inv); o[3] = f2bf(a0.w * inv);
  o[4] = f2bf(a1.x * inv); o[5] = f2bf(a1.y * inv);
  o[6] = f2bf(a1.z * inv); o[7] = f2bf(a1.w * inv);
  *(uint4*)(dst + (size_t)row * DDIM + lane * 8) = *(uint4*)o;
}

// ---------------- kernel 2: fused mask-build + LDS-staged GEMM + reductions --
// 128x128 tile per WG (4 waves, 2x2 quadrants of 64x64), BK=64, 2-barrier
// K-loop (m97 structure). Mask bits built in-kernel from idx via __ballot:
// wave reads a row-chunk (lane = col), ballot packs the 64-bit mask word in
// exactly the layout the epilogue consumes. Row counts come free as red16 of
// the float masks (popcount over the tile's columns), accumulated via P.
__global__ __launch_bounds__(256, 3) void kmain(const unsigned short* __restrict__ u,
                                                const unsigned short* __restrict__ v,
                                                const float* __restrict__ idx,
                                                const float* __restrict__ probs,
                                                float* __restrict__ P) {
  __shared__ unsigned short aT[128 * BK];   // [row][k] linear, 16 KB
  __shared__ unsigned short bT[128 * BK];   // 16 KB
  __shared__ float L0[5 * 128];
  __shared__ float L1[3 * 128];
  __shared__ u64 m0p[128][2], m0n[128][2];  // loss0 tile: rows I+r, cols J+h*64..
  __shared__ u64 m1p[128][2], m1n[128][2];  // loss1 tile: rows J+r, cols I+h*64..
  const int tid = threadIdx.x, lane = tid & 63, wid = tid >> 6;
  const int l15 = lane & 15, lg = lane >> 4;
  const int qr = wid >> 1, qc = wid & 1;

  for (int t = tid; t < 1024; t += 256) {
    if (t < 640) L0[t] = 0.f; else L1[t - 640] = 0.f;
  }

  // supertile remap (bijective over 64x64 tiles): XCD k owns ti-band k*8..k*8+7
  const int bid = blockIdx.x;
  const int xcd = bid & 7, n = bid >> 3;
  const int st = n >> 6, w = n & 63;
  const int ti = xcd * 8 + (w & 7);
  const int tj = st * 8 + (w >> 3);
  const int I = ti * 128, J = tj * 128;

  // ---- mask build: wave wid covers rows wid*32..wid*32+31 of both tiles ----
  const float th1 = probs[0], th2 = probs[1];
#pragma unroll 1
  for (int b = 0; b < 8; ++b) {           // tile0: rows I+r, cols J+h*64+lane
    float x[8];
#pragma unroll
    for (int t = 0; t < 8; ++t) {
      int i = b * 8 + t;                  // i in [0,64)
      int r = wid * 32 + (i >> 1), h = i & 1;
      x[t] = idx[(size_t)(I + r) * BDIM + J + h * 64 + lane];
    }
#pragma unroll
    for (int t = 0; t < 8; ++t) {
      int i = b * 8 + t;
      int r = wid * 32 + (i >> 1), h = i & 1;
      u64 pb = __ballot(x[t] > th1);
      u64 nb = __ballot(x[t] <= th2);
      if (lane == 0) { m0p[r][h] = pb; m0n[r][h] = nb; }
    }
  }
#pragma unroll 1
  for (int b = 0; b < 8; ++b) {           // tile1 (mirror): rows J+r, cols I+h*64+lane
    float x[8];
#pragma unroll
    for (int t = 0; t < 8; ++t) {
      int i = b * 8 + t;
      int r = wid * 32 + (i >> 1), h = i & 1;
      x[t] = idx[(size_t)(J + r) * BDIM + I + h * 64 + lane];
    }
#pragma unroll
    for (int t = 0; t < 8; ++t) {
      int i = b * 8 + t;
      int r = wid * 32 + (i >> 1), h = i & 1;
      u64 pb = __ballot(x[t] > th1);
      u64 nb = __ballot(x[t] <= th2);
      if (lane == 0) { m1p[r][h] = pb; m1n[r][h] = nb; }
    }
  }

  f32x4 acc[4][4];
#pragma unroll
  for (int a = 0; a < 4; a++)
#pragma unroll
    for (int b = 0; b < 4; b++) acc[a][b] = (f32x4){0, 0, 0, 0};

  // staging: wave wid stages rows wid*32 .. wid*32+31 of A and B.
  const unsigned short* gA = u + (size_t)(I + wid * 32 + (lane >> 3)) * DDIM + (lane & 7) * 8;
  const unsigned short* gB = v + (size_t)(J + wid * 32 + (lane >> 3)) * DDIM + (lane & 7) * 8;
  unsigned short* lA = aT + (wid * 32 + (lane >> 3)) * BK + (lane & 7) * 8;
  unsigned short* lB = bT + (wid * 32 + (lane >> 3)) * BK + (lane & 7) * 8;

  for (int k0 = 0; k0 < DDIM; k0 += BK) {
#pragma unroll
    for (int c = 0; c < 4; c++) {
      gld16(gA + (size_t)c * 8 * DDIM + k0, lA + c * 8 * BK);
      gld16(gB + (size_t)c * 8 * DDIM + k0, lB + c * 8 * BK);
    }
    __syncthreads();   // compiler drains vmcnt before barrier
#pragma unroll
    for (int kk = 0; kk < 2; kk++) {
      bf16x8 af[4], bf_[4];
#pragma unroll
      for (int ar = 0; ar < 4; ar++)
        af[ar] = *(const bf16x8*)(aT + (qr * 64 + ar * 16 + l15) * BK + kk * 32 + lg * 8);
#pragma unroll
      for (int bc = 0; bc < 4; bc++)
        bf_[bc] = *(const bf16x8*)(bT + (qc * 64 + bc * 16 + l15) * BK + kk * 32 + lg * 8);
#pragma unroll
      for (int ar = 0; ar < 4; ar++)
#pragma unroll
        for (int bc = 0; bc < 4; bc++)
          acc[ar][bc] = __builtin_amdgcn_mfma_f32_16x16x32_bf16(af[ar], bf_[bc], acc[ar][bc], 0, 0, 0);
    }
    __syncthreads();   // all reads done before next-step overwrite
  }

  // ---- preload loss1 mask words (per-lane row J+C, 2-way LDS access) ----
  u64 pw1[4], nw1[4];
#pragma unroll
  for (int bc = 0; bc < 4; bc++) {
    int C = qc * 64 + bc * 16 + l15;
    pw1[bc] = m1p[C][qr] >> (lg * 4);
    nw1[bc] = m1n[C][qr] >> (lg * 4);
  }

  float zn1[4] = {0, 0, 0, 0}, zp1[4] = {0, 0, 0, 0}, sm1[4] = {0, 0, 0, 0};

  // ---- merged pass: loss0 row stats (+row counts) + loss1 column accum ----
#pragma unroll
  for (int ar = 0; ar < 4; ar++) {
    u64 pw[4], nw[4];
#pragma unroll
    for (int j = 0; j < 4; j++) {
      int R = qr * 64 + ar * 16 + lg * 4 + j;
      pw[j] = m0p[R][qc] >> l15;          // broadcast within 16-lane group
      nw[j] = m0n[R][qc] >> l15;
    }
#pragma unroll
    for (int j = 0; j < 4; j++) {
      float zn0 = 0, zp0 = 0, sm0 = 0, cp0 = 0, cn0 = 0;
#pragma unroll
      for (int bc = 0; bc < 4; bc++) {
        float s = acc[ar][bc][j];
        float e = __expf(s - TEMP);
        float mp0 = (float)((unsigned)(pw[j]  >> (bc * 16)) & 1u);
        float mn0 = (float)((unsigned)(nw[j]  >> (bc * 16)) & 1u);
        float mp1 = (float)((unsigned)(pw1[bc] >> (ar * 16 + j)) & 1u);
        float mn1 = (float)((unsigned)(nw1[bc] >> (ar * 16 + j)) & 1u);
        zp0 = fmaf(mp0, e, zp0);
        sm0 = fmaf(mp0, s, sm0);
        zn0 = fmaf(mn0, e, zn0);
        cp0 += mp0;
        cn0 += mn0;
        zp1[bc] = fmaf(mp1, e, zp1[bc]);
        sm1[bc] = fmaf(mp1, s, sm1[bc]);
        zn1[bc] = fmaf(mn1, e, zn1[bc]);
      }
      zn0 = red16_dpp(zn0); zp0 = red16_dpp(zp0); sm0 = red16_dpp(sm0);
      cp0 = red16_dpp(cp0); cn0 = red16_dpp(cn0);
      if (l15 == 0) {
        int R = qr * 64 + ar * 16 + lg * 4 + j;
        atomicAdd(&L0[0 * 128 + R], zn0);
        atomicAdd(&L0[1 * 128 + R], zp0);
        atomicAdd(&L0[2 * 128 + R], sm0);
        atomicAdd(&L0[3 * 128 + R], cp0);
        atomicAdd(&L0[4 * 128 + R], cn0);
      }
    }
  }

  // ---- loss1: reduce over lg groups, then LDS ----
#pragma unroll
  for (int bc = 0; bc < 4; bc++) {
    float zn = zn1[bc], zp = zp1[bc], sm = sm1[bc];
    zn += __shfl_xor(zn, 16); zn += __shfl_xor(zn, 32);
    zp += __shfl_xor(zp, 16); zp += __shfl_xor(zp, 32);
    sm += __shfl_xor(sm, 16); sm += __shfl_xor(sm, 32);
    if (lg == 0) {
      int C = qc * 64 + bc * 16 + l15;
      atomicAdd(&L1[0 * 128 + C], zn);
      atomicAdd(&L1[1 * 128 + C], zp);
      atomicAdd(&L1[2 * 128 + C], sm);
    }
  }
  __syncthreads();

  // ---- write private slots (plain coalesced stores) ----
  for (int t = tid; t < 1024; t += 256) {
    int s = t >> 7, c = t & 127;
    if (s < 5) P[((size_t)tj * 8 + s) * BDIM + I + c] = L0[s * 128 + c];
    else       P[((size_t)ti * 8 + s) * BDIM + J + c] = L1[(s - 5) * 128 + c];
  }
}

// ---------------- kernel 3: reduce slots, per-row loss, block partials --------
__global__ __launch_bounds__(128) void kfinal(const float* __restrict__ P,
                                              float* __restrict__ part) {
  int r = blockIdx.x * 128 + threadIdx.x;
  float st[8] = {0, 0, 0, 0, 0, 0, 0, 0};
  for (int k = 0; k < 64; k++) {
#pragma unroll
    for (int s = 0; s < 8; s++) st[s] += P[((size_t)k * 8 + s) * BDIM + r];
  }
  float np = st[3], nn = st[4];
  float inv = 1.f / (np * (1.f + nn));
  // sum_{pos} log(1+e^{lse-s}) = np*lse - sum_pos(s) + Zp/Zn  (2nd order ~1e-11)
  float l0 = (np * (TEMP + logf(st[0])) - st[2] + st[1] / st[0]) * inv;
  float l1 = (np * (TEMP + logf(st[5])) - st[7] + st[6] / st[5]) * inv;
  float tot = l0 + l1;
#pragma unroll
  for (int m = 1; m <= 32; m <<= 1) tot += __shfl_xor(tot, m);
  __shared__ float sb;
  if (threadIdx.x == 0) sb = tot;
  __syncthreads();
  if (threadIdx.x == 64) part[blockIdx.x] = sb + tot;
}

__global__ __launch_bounds__(64) void kfinal2(const float* __restrict__ part,
                                              float* __restrict__ out) {
  float t = part[threadIdx.x];
#pragma unroll
  for (int m = 1; m <= 32; m <<= 1) t += __shfl_xor(t, m);
  if (threadIdx.x == 0) out[0] = t / (float)BDIM;
}

extern "C" void kernel_launch(void* const* d_in, const int* in_sizes, int n_in,
                              void* d_out, int out_size, void* d_ws, size_t ws_size,
                              hipStream_t stream) {
  (void)in_sizes; (void)n_in; (void)out_size; (void)ws_size;
  const float* cnn   = (const float*)d_in[0];
  const float* rnn   = (const float*)d_in[1];
  const float* idx   = (const float*)d_in[2];
  const float* probs = (const float*)d_in[3];
  char* w = (char*)d_ws;
  unsigned short* u  = (unsigned short*)w;                                   // 8 MB
  unsigned short* v  = (unsigned short*)(w + 8388608);                       // 8 MB
  float* P    = (float*)(w + 16777216);                                      // 16.78 MB
  float* part = (float*)(w + 33554432);                                      // 256 B

  knorm<<<(2 * BDIM) / 4, 256, 0, stream>>>(cnn, rnn, u, v);
  kmain<<<NT * NT, 256, 0, stream>>>(u, v, idx, probs, P);
  kfinal<<<BDIM / 128, 128, 0, stream>>>(P, part);
  kfinal2<<<1, 64, 0, stream>>>(part, (float*)d_out);
}